// Round 1
// baseline (1071.291 us; speedup 1.0000x reference)
//
#include <hip/hip_runtime.h>
#include <math.h>

#define NROWS 131072
#define NCODE 512
#define DIM 128
#define ROWS_B 64
#define CHUNK 128
#define NCHUNK (NCODE / CHUNK)
#define MARGIN 1e-4f

__global__ void e2_kernel(const float* __restrict__ emb, float* __restrict__ e2) {
    int c = blockIdx.x * blockDim.x + threadIdx.x;
    if (c < NCODE) {
        const float* e = emb + (size_t)c * DIM;
        float s = 0.f;
        #pragma unroll
        for (int l = 0; l < DIM; ++l) s = fmaf(e[l], e[l], s);
        e2[c] = s;
    }
}

__global__ __launch_bounds__(256) void vq_main(
        const float* __restrict__ x, const float* __restrict__ emb,
        const float* __restrict__ e2g, unsigned int* __restrict__ hist,
        float* __restrict__ out0, float* __restrict__ out1, float* __restrict__ out2) {
    __shared__ float xs[ROWS_B][DIM + 4];   // stride 132 floats: breaks bank aliasing
    __shared__ int s_idx[ROWS_B];
    __shared__ int s_need[ROWS_B];

    const int tid = threadIdx.x;
    const long row0 = (long)blockIdx.x * ROWS_B;

    // ---- stage x tile (64 rows x 128 f32), coalesced float4 ----
    {
        const float4* xg = reinterpret_cast<const float4*>(x + row0 * DIM);
        #pragma unroll
        for (int it = 0; it < 8; ++it) {
            int i = tid + it * 256;
            int r = i >> 5, j = i & 31;
            float4 v = xg[i];
            *reinterpret_cast<float4*>(&xs[r][j * 4]) = v;
        }
    }
    __syncthreads();

    const int tx = tid & 15;   // code-group id (16 groups x 8 codes = 128-code chunk)
    const int ty = tid >> 4;   // row-group id (16 groups x 4 rows = 64 rows)
    const int r0 = ty * 4;

    float m1[4], m2[4];
    int i1[4];
    #pragma unroll
    for (int r = 0; r < 4; ++r) { m1[r] = 1e30f; m2[r] = 1e30f; i1[r] = 0; }

    // ---- fp32 distance pass: scores s = ||e||^2 - 2*dot (x^2 is row-constant) ----
    for (int cc = 0; cc < NCHUNK; ++cc) {
        const int cbase = cc * CHUNK + tx * 8;
        const float4* eg = reinterpret_cast<const float4*>(emb + (size_t)cbase * DIM);
        float acc[4][8];
        #pragma unroll
        for (int r = 0; r < 4; ++r)
            #pragma unroll
            for (int c = 0; c < 8; ++c) acc[r][c] = 0.f;

        for (int j = 0; j < 32; ++j) {        // k in steps of 4 dims
            float4 xv[4];
            #pragma unroll
            for (int r = 0; r < 4; ++r)
                xv[r] = *reinterpret_cast<const float4*>(&xs[r0 + r][j * 4]);
            #pragma unroll
            for (int c = 0; c < 8; ++c) {
                float4 ev = eg[c * 32 + j];
                #pragma unroll
                for (int r = 0; r < 4; ++r) {
                    acc[r][c] = fmaf(xv[r].x, ev.x, acc[r][c]);
                    acc[r][c] = fmaf(xv[r].y, ev.y, acc[r][c]);
                    acc[r][c] = fmaf(xv[r].z, ev.z, acc[r][c]);
                    acc[r][c] = fmaf(xv[r].w, ev.w, acc[r][c]);
                }
            }
        }
        #pragma unroll
        for (int c = 0; c < 8; ++c) {
            int code = cbase + c;
            float ev2 = e2g[code];
            #pragma unroll
            for (int r = 0; r < 4; ++r) {
                float s = fmaf(-2.f, acc[r][c], ev2);
                if (s < m1[r])      { m2[r] = m1[r]; m1[r] = s; i1[r] = code; }
                else if (s < m2[r]) { m2[r] = s; }
            }
        }
    }

    // ---- reduce (m1,i1,m2) across the 16 code-group lanes (contiguous in-wave) ----
    #pragma unroll
    for (int r = 0; r < 4; ++r) {
        for (int off = 1; off < 16; off <<= 1) {
            float om1 = __shfl_xor(m1[r], off);
            float om2 = __shfl_xor(m2[r], off);
            int   oi1 = __shfl_xor(i1[r], off);
            bool ob = (om1 < m1[r]) || (om1 == m1[r] && oi1 < i1[r]);
            float loser = ob ? m1[r] : om1;
            m2[r] = fminf(fminf(m2[r], om2), loser);
            if (ob) { m1[r] = om1; i1[r] = oi1; }
        }
    }
    if (tx == 0) {
        #pragma unroll
        for (int r = 0; r < 4; ++r) {
            s_idx[r0 + r]  = i1[r];
            s_need[r0 + r] = (m2[r] - m1[r] < MARGIN) ? 1 : 0;
        }
    }
    __syncthreads();

    // ---- fp64 rescan for near-tie rows (~1% of rows): wave-parallel ----
    {
        const int wave = tid >> 6, lane = tid & 63;
        for (int row = wave; row < ROWS_B; row += 4) {
            if (!s_need[row]) continue;           // wave-uniform
            double best = 1e300; int bidx = NCODE;
            for (int q = 0; q < 8; ++q) {
                int code = q * 64 + lane;
                const float* e = emb + (size_t)code * DIM;
                double s = 0.0;
                for (int l = 0; l < DIM; ++l) {
                    double d = (double)xs[row][l] - (double)e[l];
                    s = fma(d, d, s);
                }
                if (s < best) { best = s; bidx = code; }
            }
            for (int off = 1; off < 64; off <<= 1) {
                double obv = __shfl_xor(best, off);
                int    oi  = __shfl_xor(bidx, off);
                if (obv < best || (obv == best && oi < bidx)) { best = obv; bidx = oi; }
            }
            if (lane == 0) s_idx[row] = bidx;
        }
    }
    __syncthreads();

    // ---- out0: gather selected codebook rows (exact fp32 copy) ----
    #pragma unroll
    for (int it = 0; it < 8; ++it) {
        int i = tid + it * 256;
        int r = i >> 5, j = i & 31;
        int code = s_idx[r];
        float4 v = *reinterpret_cast<const float4*>(emb + (size_t)code * DIM + j * 4);
        *reinterpret_cast<float4*>(out0 + (row0 + r) * DIM + j * 4) = v;
    }

    // ---- out1/out2: per-row ||x - e_sel||^2 (4 lanes per row) ----
    {
        int row = tid >> 2, part = tid & 3;
        int code = s_idx[row];
        const float* e  = emb + (size_t)code * DIM + part * 32;
        const float* xr = &xs[row][part * 32];
        float s = 0.f;
        #pragma unroll
        for (int l = 0; l < 32; ++l) { float d = xr[l] - e[l]; s = fmaf(d, d, s); }
        s += __shfl_down(s, 1);
        s += __shfl_down(s, 2);
        if (part == 0) { out1[row0 + row] = s; out2[row0 + row] = s; }
    }

    // ---- histogram ----
    if (tid < ROWS_B) atomicAdd(&hist[s_idx[tid]], 1u);
}

__global__ void entropy_kernel(const unsigned int* __restrict__ hist, float* __restrict__ oent) {
    __shared__ float red[8];
    int tid = threadIdx.x;  // 512 threads
    float p = (float)hist[tid] * (1.0f / 131072.0f);   // /2^17: exact
    float t = (p > 0.f) ? (-p * logf(p)) : 0.f;
    #pragma unroll
    for (int off = 32; off > 0; off >>= 1) t += __shfl_down(t, off);
    if ((tid & 63) == 0) red[tid >> 6] = t;
    __syncthreads();
    if (tid == 0) {
        float s = 0.f;
        #pragma unroll
        for (int i = 0; i < 8; ++i) s += red[i];
        *oent = s;
    }
}

extern "C" void kernel_launch(void* const* d_in, const int* in_sizes, int n_in,
                              void* d_out, int out_size, void* d_ws, size_t ws_size,
                              hipStream_t stream) {
    const float* x   = (const float*)d_in[0];
    const float* emb = (const float*)d_in[1];
    float* out  = (float*)d_out;
    float* out0 = out;
    float* out1 = out0 + (size_t)NROWS * DIM;
    float* out2 = out1 + NROWS;
    float* oent = out2 + NROWS;

    unsigned int* hist = (unsigned int*)d_ws;
    float* e2 = (float*)((char*)d_ws + 4096);

    hipMemsetAsync(d_ws, 0, 4096, stream);                       // zero histogram (ws is poisoned)
    e2_kernel<<<2, 256, 0, stream>>>(emb, e2);
    vq_main<<<NROWS / ROWS_B, 256, 0, stream>>>(x, emb, e2, hist, out0, out1, out2);
    entropy_kernel<<<1, 512, 0, stream>>>(hist, oent);
}

// Round 2
// 159.828 us; speedup vs baseline: 6.7028x; 6.7028x over previous
//
#include <hip/hip_runtime.h>
#include <hip/hip_bf16.h>
#include <math.h>

#define NROWS 131072
#define NCODE 512
#define DIM 128
#define ROWS_B 64
#define MARGIN 2e-5f

typedef __attribute__((ext_vector_type(8))) short short8v;
typedef __attribute__((ext_vector_type(16))) float f32x16;

__device__ inline short f2bf(float v) {
    __hip_bfloat16 h = __float2bfloat16(v);
    return *reinterpret_cast<short*>(&h);
}
__device__ inline float bf2f(short s) {
    __hip_bfloat16 h;
    *reinterpret_cast<short*>(&h) = s;
    return __bfloat162float(h);
}

// emb fp32 [512][128] -> bf16 hi/lo split + ||e||^2
__global__ __launch_bounds__(256) void prep_kernel(const float* __restrict__ emb,
        short* __restrict__ ehi, short* __restrict__ elo, float* __restrict__ e2g) {
    int gidx = blockIdx.x * 256 + threadIdx.x;      // 64 blocks * 256 = 16384 float4s
    int code = gidx >> 5, j = gidx & 31;
    float4 v = reinterpret_cast<const float4*>(emb)[gidx];
    short4 h, l;
    h.x = f2bf(v.x); h.y = f2bf(v.y); h.z = f2bf(v.z); h.w = f2bf(v.w);
    l.x = f2bf(v.x - bf2f(h.x));
    l.y = f2bf(v.y - bf2f(h.y));
    l.z = f2bf(v.z - bf2f(h.z));
    l.w = f2bf(v.w - bf2f(h.w));
    *reinterpret_cast<short4*>(ehi + code * DIM + j * 4) = h;
    *reinterpret_cast<short4*>(elo + code * DIM + j * 4) = l;
    float ss = v.x * v.x + v.y * v.y + v.z * v.z + v.w * v.w;
    ss += __shfl_down(ss, 16, 32); ss += __shfl_down(ss, 8, 32);
    ss += __shfl_down(ss, 4, 32);  ss += __shfl_down(ss, 2, 32);
    ss += __shfl_down(ss, 1, 32);
    if ((threadIdx.x & 31) == 0) e2g[code] = ss;
}

#define MFMA3(ACC, AH, AL, BH, BL)                                         \
    ACC = __builtin_amdgcn_mfma_f32_32x32x16_bf16(AH, BH, ACC, 0, 0, 0);   \
    ACC = __builtin_amdgcn_mfma_f32_32x32x16_bf16(AH, BL, ACC, 0, 0, 0);   \
    ACC = __builtin_amdgcn_mfma_f32_32x32x16_bf16(AL, BH, ACC, 0, 0, 0);

// D[m][n]: m = code (reg-mapped), n = row (col = lane&31)  -> per-row min is lane-local
#define PROC(ACC, MT, NT)                                                  \
    _Pragma("unroll")                                                      \
    for (int r = 0; r < 16; ++r) {                                         \
        int code = cbase + (MT) * 32 + (r & 3) + 8 * (r >> 2) + 4 * g;     \
        float sv = e2s[code] - 2.0f * (ACC)[r];                            \
        bool lt = sv < m1_##NT;                                            \
        m2_##NT = lt ? m1_##NT : fminf(m2_##NT, sv);                       \
        if (lt) { m1_##NT = sv; i1_##NT = code; }                          \
    }

#define XMERGE(NT) {                                                       \
    float pm1 = __shfl_xor(m1_##NT, 32);                                   \
    float pm2 = __shfl_xor(m2_##NT, 32);                                   \
    int   pi  = __shfl_xor(i1_##NT, 32);                                   \
    bool pb = (pm1 < m1_##NT) || (pm1 == m1_##NT && pi < i1_##NT);         \
    float loser = pb ? m1_##NT : pm1;                                      \
    m2_##NT = fminf(fminf(m2_##NT, pm2), loser);                           \
    if (pb) { m1_##NT = pm1; i1_##NT = pi; }                               \
}

__global__ __launch_bounds__(256, 2) void vq_main(
        const float* __restrict__ x, const float* __restrict__ emb,
        const short* __restrict__ ehi, const short* __restrict__ elo,
        const float* __restrict__ e2g, unsigned int* __restrict__ hist,
        float* __restrict__ out0, float* __restrict__ out1, float* __restrict__ out2) {
    __shared__ short xs_hi[ROWS_B][DIM];   // XOR-swizzled: short index d ^ ((row&15)<<3)
    __shared__ short xs_lo[ROWS_B][DIM];
    __shared__ float e2s[NCODE];
    __shared__ float x2s[ROWS_B];
    __shared__ float wm1[4][ROWS_B], wm2[4][ROWS_B];
    __shared__ int   wi1[4][ROWS_B];
    __shared__ int   s_idx[ROWS_B];
    __shared__ float s_fin[ROWS_B];
    __shared__ int   s_need[ROWS_B];

    const int tid = threadIdx.x;
    const long row0 = (long)blockIdx.x * ROWS_B;

    // ---- stage x -> bf16 hi/lo in LDS (swizzled), coalesced float4 ----
    const float4* xg = reinterpret_cast<const float4*>(x + row0 * DIM);
    #pragma unroll
    for (int it = 0; it < 8; ++it) {
        int i = tid + it * 256;
        int r = i >> 5, d0 = (i & 31) * 4;
        float4 v = xg[i];
        short4 h, l;
        h.x = f2bf(v.x); h.y = f2bf(v.y); h.z = f2bf(v.z); h.w = f2bf(v.w);
        l.x = f2bf(v.x - bf2f(h.x));
        l.y = f2bf(v.y - bf2f(h.y));
        l.z = f2bf(v.z - bf2f(h.z));
        l.w = f2bf(v.w - bf2f(h.w));
        int dd = d0 ^ ((r & 15) << 3);
        *reinterpret_cast<short4*>(&xs_hi[r][dd]) = h;
        *reinterpret_cast<short4*>(&xs_lo[r][dd]) = l;
    }
    for (int i = tid; i < NCODE; i += 256) e2s[i] = e2g[i];
    // ---- x2 per row (fp32, from global; L1/L2-hot) ----
    {
        int r = tid >> 2, q = tid & 3;
        const float4* xr = reinterpret_cast<const float4*>(x + (row0 + r) * DIM + q * 32);
        float s = 0.f;
        #pragma unroll
        for (int jj = 0; jj < 8; ++jj) {
            float4 v = xr[jj];
            s = fmaf(v.x, v.x, s); s = fmaf(v.y, v.y, s);
            s = fmaf(v.z, v.z, s); s = fmaf(v.w, v.w, s);
        }
        s += __shfl_down(s, 1, 64);
        s += __shfl_down(s, 2, 64);
        if (q == 0) x2s[r] = s;
    }
    __syncthreads();

    const int wv = tid >> 6, lane = tid & 63;
    const int l31 = lane & 31, g = lane >> 5;
    const int cbase = wv * 128;

    f32x16 acc00 = {}, acc10 = {}, acc20 = {}, acc30 = {};
    f32x16 acc01 = {}, acc11 = {}, acc21 = {}, acc31 = {};

    // A (emb codes): lane holds code = cbase + mt*32 + l31, dims k0 + g*8 .. +8
    const int arow = (cbase + l31) * DIM + g * 8;
    const int bsw = (l31 & 15) << 3;           // same for rows l31 and 32+l31
    for (int kk = 0; kk < 8; ++kk) {
        const int k0 = kk * 16;
        short8v ah0 = *reinterpret_cast<const short8v*>(ehi + arow + k0);
        short8v ah1 = *reinterpret_cast<const short8v*>(ehi + arow + 4096 + k0);
        short8v ah2 = *reinterpret_cast<const short8v*>(ehi + arow + 8192 + k0);
        short8v ah3 = *reinterpret_cast<const short8v*>(ehi + arow + 12288 + k0);
        short8v al0 = *reinterpret_cast<const short8v*>(elo + arow + k0);
        short8v al1 = *reinterpret_cast<const short8v*>(elo + arow + 4096 + k0);
        short8v al2 = *reinterpret_cast<const short8v*>(elo + arow + 8192 + k0);
        short8v al3 = *reinterpret_cast<const short8v*>(elo + arow + 12288 + k0);
        int dd = (k0 + g * 8) ^ bsw;
        short8v bh0 = *reinterpret_cast<const short8v*>(&xs_hi[l31][dd]);
        short8v bh1 = *reinterpret_cast<const short8v*>(&xs_hi[32 + l31][dd]);
        short8v bl0 = *reinterpret_cast<const short8v*>(&xs_lo[l31][dd]);
        short8v bl1 = *reinterpret_cast<const short8v*>(&xs_lo[32 + l31][dd]);
        MFMA3(acc00, ah0, al0, bh0, bl0);
        MFMA3(acc10, ah1, al1, bh0, bl0);
        MFMA3(acc20, ah2, al2, bh0, bl0);
        MFMA3(acc30, ah3, al3, bh0, bl0);
        MFMA3(acc01, ah0, al0, bh1, bl1);
        MFMA3(acc11, ah1, al1, bh1, bl1);
        MFMA3(acc21, ah2, al2, bh1, bl1);
        MFMA3(acc31, ah3, al3, bh1, bl1);
    }

    // ---- per-lane min over 64 codes per row, track (m1, i1, m2) ----
    float m1_0 = 1e30f, m2_0 = 1e30f; int i1_0 = 0;
    float m1_1 = 1e30f, m2_1 = 1e30f; int i1_1 = 0;
    PROC(acc00, 0, 0) PROC(acc10, 1, 0) PROC(acc20, 2, 0) PROC(acc30, 3, 0)
    PROC(acc01, 0, 1) PROC(acc11, 1, 1) PROC(acc21, 2, 1) PROC(acc31, 3, 1)
    // merge complementary code-halves (lane r <-> r+32, same row)
    XMERGE(0)
    XMERGE(1)
    if (lane < 32) {
        wm1[wv][l31] = m1_0; wm2[wv][l31] = m2_0; wi1[wv][l31] = i1_0;
        wm1[wv][32 + l31] = m1_1; wm2[wv][32 + l31] = m2_1; wi1[wv][32 + l31] = i1_1;
    }
    __syncthreads();

    // ---- cross-wave merge (4 code-groups), margin test ----
    if (tid < ROWS_B) {
        float m1 = wm1[0][tid], m2 = wm2[0][tid]; int i1 = wi1[0][tid];
        #pragma unroll
        for (int w = 1; w < 4; ++w) {
            float pm1 = wm1[w][tid], pm2 = wm2[w][tid]; int pi = wi1[w][tid];
            bool pb = (pm1 < m1) || (pm1 == m1 && pi < i1);
            float loser = pb ? m1 : pm1;
            m2 = fminf(fminf(m2, pm2), loser);
            if (pb) { m1 = pm1; i1 = pi; }
        }
        s_idx[tid] = i1; s_fin[tid] = m1;
        s_need[tid] = (m2 - m1 < MARGIN) ? 1 : 0;
    }
    __syncthreads();

    // ---- fp64 rescue for near-tie rows (exact argmin, lowest-index ties) ----
    for (int row = wv; row < ROWS_B; row += 4) {
        if (!s_need[row]) continue;            // wave-uniform
        const float4* xr = reinterpret_cast<const float4*>(x + (row0 + row) * DIM);
        double best = 1e300; int bi = NCODE;
        for (int q = 0; q < 8; ++q) {
            int code = q * 64 + lane;
            const float4* er = reinterpret_cast<const float4*>(emb + (size_t)code * DIM);
            double s = 0.0;
            for (int j = 0; j < 32; ++j) {
                float4 xv = xr[j];
                float4 ev = er[j];
                double d0 = (double)xv.x - (double)ev.x;
                double d1 = (double)xv.y - (double)ev.y;
                double d2 = (double)xv.z - (double)ev.z;
                double d3 = (double)xv.w - (double)ev.w;
                s = fma(d0, d0, s); s = fma(d1, d1, s);
                s = fma(d2, d2, s); s = fma(d3, d3, s);
            }
            if (s < best) { best = s; bi = code; }   // ascending q -> lowest index kept
        }
        for (int off = 1; off < 64; off <<= 1) {
            double ob = __shfl_xor(best, off);
            int    oi = __shfl_xor(bi, off);
            if (ob < best || (ob == best && oi < bi)) { best = ob; bi = oi; }
        }
        if (lane == 0) {
            s_idx[row] = bi;
            s_fin[row] = (float)best - x2s[row];
        }
    }
    __syncthreads();

    // ---- out0: gather selected codebook rows (exact fp32) ----
    float4* o0 = reinterpret_cast<float4*>(out0 + row0 * DIM);
    #pragma unroll
    for (int it = 0; it < 8; ++it) {
        int i = tid + it * 256;
        int r = i >> 5, j = i & 31;
        int code = s_idx[r];
        o0[i] = reinterpret_cast<const float4*>(emb + (size_t)code * DIM)[j];
    }
    // ---- out1/out2 + histogram ----
    if (tid < ROWS_B) {
        float o = x2s[tid] + s_fin[tid];
        out1[row0 + tid] = o;
        out2[row0 + tid] = o;
        atomicAdd(&hist[s_idx[tid]], 1u);
    }
}

__global__ void entropy_kernel(const unsigned int* __restrict__ hist, float* __restrict__ oent) {
    __shared__ float red[8];
    int tid = threadIdx.x;  // 512 threads
    float p = (float)hist[tid] * (1.0f / 131072.0f);
    float t = (p > 0.f) ? (-p * logf(p)) : 0.f;
    #pragma unroll
    for (int off = 32; off > 0; off >>= 1) t += __shfl_down(t, off);
    if ((tid & 63) == 0) red[tid >> 6] = t;
    __syncthreads();
    if (tid == 0) {
        float s = 0.f;
        #pragma unroll
        for (int i = 0; i < 8; ++i) s += red[i];
        *oent = s;
    }
}

extern "C" void kernel_launch(void* const* d_in, const int* in_sizes, int n_in,
                              void* d_out, int out_size, void* d_ws, size_t ws_size,
                              hipStream_t stream) {
    const float* x   = (const float*)d_in[0];
    const float* emb = (const float*)d_in[1];
    float* out  = (float*)d_out;
    float* out0 = out;
    float* out1 = out0 + (size_t)NROWS * DIM;
    float* out2 = out1 + NROWS;
    float* oent = out2 + NROWS;

    unsigned int* hist = (unsigned int*)d_ws;
    float* e2g = (float*)((char*)d_ws + 4096);
    short* ehi = (short*)((char*)d_ws + 8192);
    short* elo = (short*)((char*)d_ws + 8192 + NCODE * DIM * 2);

    hipMemsetAsync(d_ws, 0, 4096, stream);   // zero histogram (ws is poisoned, not re-zeroed)
    prep_kernel<<<NCODE * DIM / (4 * 256), 256, 0, stream>>>(emb, ehi, elo, e2g);
    vq_main<<<NROWS / ROWS_B, 256, 0, stream>>>(x, emb, ehi, elo, e2g, hist, out0, out1, out2);
    entropy_kernel<<<1, NCODE, 0, stream>>>(hist, oent);
}